// Round 24
// baseline (1445.971 us; speedup 1.0000x reference)
//
#include <hip/hip_runtime.h>
#include <math.h>

// FWI forward: 10 shots, 1000 steps, padded grid 130x160 (NBC=30).
// R24 = R23's x-halo-via-shuffle with the WAVE-BOUNDARY BUG fixed.
// R23 failed (absmax 5.7): 40-thread rows straddle 64-lane waves (tid 63 /
// tid 64 are the same row, different waves) and __shfl can't cross waves.
// Fix: lanes 0 and 63 of each wave patch their cross-wave x-halo side from
// the PR LDS buffer (provably == neighbor's CUR regs: every active thread
// wrote its rows to the read buffer last sub-step; same-gr threads share
// actk). Grid-edge zero-select (qx==0/39) applied AFTER, overriding.
// Cost: 2 divergent b64/wave/row (~64/block-step vs 4096 in R22) -> the
// LDS-traffic win (10 -> 6 instrs/thread-step) survives.

#define SROW 168                 // Ps row stride; col = x + 4
#define PS_ROWS 52               // slots -2..49
#define PSZ (PS_ROWS * SROW)
#define RH 2
#define DTf 0.0008f
#define C2f 1.3333333333333333f
#define C3f (-0.08333333333333333f)

#define CST_OFF 4096
#define G_OFF   262144           // bytes; 4 bufs x 10 shots x 10400 u64
#define FLAG_OFF 3590144         // bytes; 80 u32
#define GSEG 10400               // u64 per (buf, shot) = 130 rows x 80

#define LD4(arr, i) (*reinterpret_cast<const float4*>(&(arr)[i]))
#define LD2(arr, i) (*reinterpret_cast<const float2*>(&(arr)[i]))
#define ST4(arr, i, v) (*reinterpret_cast<float4*>(&(arr)[i]) = (v))

// ---------- setup 1: velmin, wavelet, amps, zero flags ----------
__global__ __launch_bounds__(1024) void fwi_setup1(const float* __restrict__ v,
                                                   float* __restrict__ ws,
                                                   unsigned int* __restrict__ flags) {
    int tid = threadIdx.x;
    if (tid < 80) flags[tid] = 0u;
    float m = 3.402823466e38f;
    for (int i = tid; i < 7000; i += 1024) m = fminf(m, v[i]);
    #pragma unroll
    for (int off = 32; off > 0; off >>= 1) m = fminf(m, __shfl_down(m, off, 64));
    __shared__ float red[16];
    if ((tid & 63) == 0) red[tid >> 6] = m;
    __syncthreads();
    if (tid == 0) {
        float mm = red[0];
        for (int i = 1; i < 16; ++i) mm = fminf(mm, red[i]);
        ws[1010] = mm * 1000.0f + 3000.0f;
    }
    if (tid < 1000) {
        float w = 0.0f;
        if (tid < 111) {
            float a = (float)(55 - tid) * 0.06283185307179587f;
            float b = a * a;
            w = (1.0f - 2.0f * b) * expf(-b);
        }
        ws[tid] = w;
    }
    if (tid >= 1000 && tid < 1010) {
        int l = tid - 1000;
        float vd = v[100 + 11 * l] * 1000.0f + 3000.0f;
        float bdt = vd * DTf;
        ws[tid] = bdt * bdt;
    }
}

// ---------- setup 2: interleaved per-quad constants CST[quad] = {AL4,T14,T2n4} ----------
__global__ __launch_bounds__(256) void fwi_setup2(const float* __restrict__ v,
                                                  const float* __restrict__ ws,
                                                  float* __restrict__ CST) {
    int c = blockIdx.x * 256 + threadIdx.x;
    if (c >= 130 * 160) return;
    float velmin = ws[1010];
    int z = c / 160;
    int x = c - z * 160;
    int iz = min(max(z - 30, 0), 69);
    int ix = min(max(x - 30, 0), 99);
    float vd = v[iz * 100 + ix] * 1000.0f + 3000.0f;
    float tt = vd * DTf / 10.0f;
    float al = tt * tt;
    int qx = max(29 - x, x - 130);
    int qz = max(29 - z, z - 100);
    int q = (qx >= 0) ? qx : qz;
    float kdt = 0.0f;
    if (q >= 0) {
        float kap3 = 3.0f * velmin * 16.118095650958319f / 580.0f;
        float r = (float)q * (10.0f / 290.0f);
        kdt = kap3 * (r * r) * DTf;
    }
    int quad = c >> 2, j = c & 3;
    CST[quad * 12 + j]     = al;
    CST[quad * 12 + 4 + j] = 2.0f - 5.0f * al - kdt;  // temp1
    CST[quad * 12 + 8 + j] = kdt - 1.0f;              // negated temp2
}

static __device__ __forceinline__ float cellq(float l2, float l1, float cc, float r1, float r2,
                                              float u1, float u2, float d1, float d2,
                                              float al, float t1, float t2n, float p0) {
    float lap = C2f * ((l1 + r1) + (u1 + d1)) + C3f * ((l2 + r2) + (u2 + d2));
    return (t1 * cc + t2n * p0) + al * lap;
}

static __device__ __forceinline__ float4 ld_remote16(const unsigned long long* p) {
    union { unsigned long long u; float2 f; } a, b;
    a.u = __hip_atomic_load(p,     __ATOMIC_RELAXED, __HIP_MEMORY_SCOPE_AGENT);
    b.u = __hip_atomic_load(p + 1, __ATOMIC_RELAXED, __HIP_MEMORY_SCOPE_AGENT);
    return make_float4(a.f.x, a.f.y, b.f.x, b.f.y);
}
static __device__ __forceinline__ void st_remote16(unsigned long long* p, float4 v) {
    union { unsigned long long u; float2 f; } c;
    c.f = make_float2(v.x, v.y);
    __hip_atomic_store(p,     c.u, __ATOMIC_RELAXED, __HIP_MEMORY_SCOPE_AGENT);
    c.f = make_float2(v.z, v.w);
    __hip_atomic_store(p + 1, c.u, __ATOMIC_RELAXED, __HIP_MEMORY_SCOPE_AGENT);
}

// One cell-row update (4 cells). Produces q from CUR/OLD regs + halos.
#define ROWQ4(q, c, p0, hl, hr, u1, u2, d1, d2, al4, t14, t24) do {             \
    (q).x = cellq((hl).x, (hl).y, (c).x, (c).y, (c).z,                          \
                  (u1).x, (u2).x, (d1).x, (d2).x, (al4).x, (t14).x, (t24).x, (p0).x); \
    (q).y = cellq((hl).y, (c).x, (c).y, (c).z, (c).w,                           \
                  (u1).y, (u2).y, (d1).y, (d2).y, (al4).y, (t14).y, (t24).y, (p0).y); \
    (q).z = cellq((c).x, (c).y, (c).z, (c).w, (hr).x,                           \
                  (u1).z, (u2).z, (d1).z, (d2).z, (al4).z, (t14).z, (t24).z, (p0).z); \
    (q).w = cellq((c).y, (c).z, (c).w, (hr).x, (hr).y,                          \
                  (u1).w, (u2).w, (d1).w, (d2).w, (al4).w, (t14).w, (t24).w, (p0).w); \
} while (0)

// x-halo: shuffle from adjacent lanes; lanes 0/63 patch the cross-wave side
// from PR (same values as neighbor regs); grid edges zero-selected LAST.
#define XHALO(hl, hr, c, PR, rb) do {                                           \
    (hl).x = __shfl_up((c).z, 1, 64);                                           \
    (hl).y = __shfl_up((c).w, 1, 64);                                           \
    (hr).x = __shfl_down((c).x, 1, 64);                                         \
    (hr).y = __shfl_down((c).y, 1, 64);                                         \
    if (lane == 0 && qx != 0)   { (hl) = LD2(PR, (rb) - 2); }                   \
    if (lane == 63 && qx != 39) { (hr) = LD2(PR, (rb) + 4); }                   \
    if (qx == 0)  { (hl).x = 0.0f; (hl).y = 0.0f; }                             \
    if (qx == 39) { (hr).x = 0.0f; (hr).y = 0.0f; }                             \
} while (0)

// One sub-step (RH=2). CUR = p1 regs (read-only), OLD = p0 regs (overwritten
// with new p1). K = sub-step index (0..7) for validity creep. EXPF: inline
// epoch export (k==7 only; creep-active set == interior owners there).
#define STEP(CUR, OLD, T, K, EXPF, EPAR, PR, PW) do {                           \
    const int Ti = (T);                                                         \
    const int kp1 = (K) + 1;                                                    \
    const bool actk = act && (gr >= (ct ? kp1 : 0)) && (gr < ng - (cb ? kp1 : 0)); \
    const float as = (Ti < 111) ? amp * Wv[Ti] : 0.0f;                          \
    if (actk) {                                                                 \
        float4 hu2 = LD4(PR, pc0 - 2 * SROW);                                   \
        float4 hu1 = LD4(PR, pc0 - SROW);                                       \
        float4 hd1 = LD4(PR, pc0 + 2 * SROW);                                   \
        float4 hd2 = LD4(PR, pc0 + 3 * SROW);                                   \
        float2 hl0, hr0, hl1, hr1;                                              \
        XHALO(hl0, hr0, (CUR)[0], PR, pc0);                                     \
        XHALO(hl1, hr1, (CUR)[1], PR, pc0 + SROW);                              \
        float4 q0, q1;                                                          \
        ROWQ4(q0, (CUR)[0], (OLD)[0], hl0, hr0, hu1, hu2, (CUR)[1], hd1, ca0, ct0, cs0); \
        ROWQ4(q1, (CUR)[1], (OLD)[1], hl1, hr1, (CUR)[0], hu1, hd1, hd2, ca1, ct1, cs1); \
        if (src0) {                                /* source row at slot gr*2 */ \
            q0.x += (ls == 0) ? as : 0.0f;                                      \
            q0.y += (ls == 1) ? as : 0.0f;                                      \
            q0.z += (ls == 2) ? as : 0.0f;                                      \
            q0.w += (ls == 3) ? as : 0.0f;                                      \
        }                                                                       \
        if (src1) {                                /* source row at slot gr*2+1 */ \
            q1.x += (ls == 0) ? as : 0.0f;                                      \
            q1.y += (ls == 1) ? as : 0.0f;                                      \
            q1.z += (ls == 2) ? as : 0.0f;                                      \
            q1.w += (ls == 3) ? as : 0.0f;                                      \
        }                                                                       \
        if (grec) {                                /* receivers: global row 31 */ \
            const int ob = shot * 100000 + Ti * 100 + xr0;                      \
            if (xr0 >= 0  && xr0 <= 99) out[ob]     = q1.x;                     \
            if (xr0 >= -1 && xr0 <= 98) out[ob + 1] = q1.y;                     \
            if (xr0 >= -2 && xr0 <= 97) out[ob + 2] = q1.z;                     \
            if (xr0 >= -3 && xr0 <= 96) out[ob + 3] = q1.w;                     \
        }                                                                       \
        if ((EXPF) && exp01) {                     /* inline epoch export */    \
            const size_t po = (size_t)((EPAR) * 20) * GSEG;                     \
            st_remote16(Gu + po + eb0, q0);                                     \
            st_remote16(Gu + po + (size_t)10 * GSEG + eb0, (CUR)[0]);           \
            st_remote16(Gu + po + eb1, q1);                                     \
            st_remote16(Gu + po + (size_t)10 * GSEG + eb1, (CUR)[1]);           \
        }                                                                       \
        (OLD)[0] = q0; (OLD)[1] = q1;                                           \
        ST4(PW, pc0, q0);                                                       \
        ST4(PW, pc0 + SROW, q1);                                                \
    }                                                                           \
    __syncthreads();            /* PW complete, PR reads done, exports drained */ \
} while (0)

// Epoch exchange tail: flag release + CENTRAL poll (2 threads) + barrier +
// relaxed import + barrier. R16/R20-proven happens-before chain.
#define EXCHANGE(E) do {                                                        \
    const int par = (E) & 1;                                                    \
    const size_t po1 = (size_t)(par * 20) * GSEG;                               \
    const size_t po0 = po1 + (size_t)10 * GSEG;                                 \
    if (tid == 0)                                                               \
        __hip_atomic_store(&flags[(shot << 3) + seg], (unsigned)(E) + 1u,       \
                           __ATOMIC_RELEASE, __HIP_MEMORY_SCOPE_AGENT);         \
    if (tid == 64 && ct)                                                        \
        while (__hip_atomic_load(&flags[(shot << 3) + seg - 1], __ATOMIC_ACQUIRE,\
                                 __HIP_MEMORY_SCOPE_AGENT) <= (unsigned)(E)) {} \
    if (tid == 128 && cb)                                                       \
        while (__hip_atomic_load(&flags[(shot << 3) + seg + 1], __ATOMIC_ACQUIRE,\
                                 __HIP_MEMORY_SCOPE_AGENT) <= (unsigned)(E)) {} \
    __syncthreads();                        /* neighbors' data ready */         \
    if (act && halo_thr) {                                                      \
        float4 v1a = ld_remote16(Gu + po1 + eb0);                               \
        float4 v0a = ld_remote16(Gu + po0 + eb0);                               \
        float4 v1b = ld_remote16(Gu + po1 + eb1);                               \
        float4 v0b = ld_remote16(Gu + po0 + eb1);                               \
        pB[0] = v1a; pA[0] = v0a;                                               \
        pB[1] = v1b; pA[1] = v0b;                                               \
        ST4(PsA, pc0, v1a);                                                     \
        ST4(PsA, pc0 + SROW, v1b);                                              \
    }                                                                           \
    __syncthreads();                        /* imported PsA/regs visible */     \
} while (0)

// ---------- main: 80 blocks = 10 shots x 8 z-segments, 1024 threads ----------
__global__ __launch_bounds__(1024, 4) void fwi_main(const float4* __restrict__ CST4,
                                                    const float* __restrict__ ws,
                                                    unsigned long long* __restrict__ Gu,
                                                    unsigned int* __restrict__ flags,
                                                    float* __restrict__ out) {
    __shared__ float PsA[PSZ];     // p1 mirror, even-T read buffer (34,944 B)
    __shared__ float PsB[PSZ];     // p1 mirror, odd-T read buffer (34,944 B)
    __shared__ float Wv[1024];     // wavelet, zero-padded
    const int tid = threadIdx.x;
    const int bid = blockIdx.x;
    const int shot = bid >> 3, seg = bid & 7;

    for (int i = tid; i < PSZ; i += 1024) { PsA[i] = 0.0f; PsB[i] = 0.0f; }
    Wv[tid] = (tid < 111) ? ws[tid] : 0.0f;

    const int int_base = 16 * seg;                 // interior global start row
    const int int_n = (seg < 7) ? 16 : 18;         // interior rows
    const int base = (seg > 0) ? int_base - 16 : 0;// stored global start row
    const int halo_top = (seg > 0) ? 16 : 0;
    const int stored_n = halo_top + int_n + ((seg < 7) ? 16 : 0); // 32|48|34 (even)
    const bool ct = (seg > 0);                     // top cut exists
    const bool cb = (seg < 7);                     // bottom cut exists
    const int ng = stored_n >> 1;                  // groups covering stored rows

    const int gr = tid / 40;                       // z-group 0..24 (RH=2 rows)
    const int qx = tid - gr * 40;                  // x-quad 0..39
    const int lane = tid & 63;                     // wave lane (shuffle domain)
    const bool act = (gr < 24) && (gr * 2 < stored_n);
    const float amp = ws[1000 + shot];
    const int xs = 30 + 11 * shot;
    const bool isq = (qx == (xs >> 2));
    const int ls = xs & 3;
    const int s31 = 31 - base;                     // stored slot of source row
    const bool src0 = act && isq && (gr * 2 == s31);
    const bool src1 = act && isq && (gr * 2 + 1 == s31);
    const int pc0 = (gr * 2 + 2) * SROW + 4 * qx + 4;
    const float4* cst = CST4 + (size_t)((base + gr * 2) * 40 + qx) * 3;
    const bool grec = (seg == 1) && (gr == 15);    // slot 31 = global row 31 (r=1)
    const int xr0 = 4 * qx - 30;                   // receiver index of lane j=0

    // exchange addressing (group-aligned: interior/halo bounds are even)
    const int slot0 = gr * 2;
    const bool exp01 = (slot0 >= halo_top) && (slot0 < halo_top + int_n);
    const bool top_h = (slot0 < halo_top);                    // implies seg>0
    const bool bot_h = (slot0 >= halo_top + int_n) && (slot0 < stored_n); // implies seg<7
    const bool halo_thr = top_h || bot_h;
    const size_t eb0 = (size_t)shot * GSEG + (size_t)(base + slot0) * 80 + 2 * qx;
    const size_t eb1 = eb0 + 80;

    // hoisted time-invariant coefficients (24 VGPRs)
    float4 ca0, ct0, cs0, ca1, ct1, cs1;
    ca0 = ct0 = cs0 = ca1 = ct1 = cs1 = make_float4(0.f, 0.f, 0.f, 0.f);
    if (act) {
        ca0 = cst[0];   ct0 = cst[1];   cs0 = cst[2];
        ca1 = cst[120]; ct1 = cst[121]; cs1 = cst[122];
    }

    float4 pA[RH], pB[RH];                         // two generations in regs
    #pragma unroll
    for (int r = 0; r < RH; ++r) {
        pA[r] = make_float4(0.f, 0.f, 0.f, 0.f);
        pB[r] = make_float4(0.f, 0.f, 0.f, 0.f);
    }
    __syncthreads();

    for (int e = 0; e < 125; ++e) {                // 125 epochs x 8 sub-steps
        #pragma unroll
        for (int kk = 0; kk < 4; ++kk) {
            STEP(pB, pA, e * 8 + 2 * kk,     2 * kk,     false,      0,     PsA, PsB);
            STEP(pA, pB, e * 8 + 2 * kk + 1, 2 * kk + 1, (kk == 3), (e & 1), PsB, PsA);
        }
        if (e < 124) EXCHANGE(e);
    }
}

extern "C" void kernel_launch(void* const* d_in, const int* in_sizes, int n_in,
                              void* d_out, int out_size, void* d_ws, size_t ws_size,
                              hipStream_t stream) {
    const float* v = (const float*)d_in[0];
    float* ws = (float*)d_ws;
    float* CST = (float*)((char*)d_ws + CST_OFF);
    unsigned long long* Gu = (unsigned long long*)((char*)d_ws + G_OFF);
    unsigned int* flags = (unsigned int*)((char*)d_ws + FLAG_OFF);
    float* out = (float*)d_out;

    fwi_setup1<<<1, 1024, 0, stream>>>(v, ws, flags);
    fwi_setup2<<<82, 256, 0, stream>>>(v, ws, CST);
    fwi_main<<<80, 1024, 0, stream>>>((const float4*)CST, ws, Gu, flags, out);
}

// Round 25
// 1241.785 us; speedup vs baseline: 1.1644x; 1.1644x over previous
//
#include <hip/hip_runtime.h>
#include <math.h>

// FWI forward: 10 shots, 1000 steps, padded grid 130x160 (NBC=30).
// R25 = R22 verbatim (measured best: 1,243us). R23/R24's shuffle x-halo
// REGRESSED (+16% despite -64% bank conflicts): the b64 x-halo LDS reads
// co-issue with compute and are NOT critical-path; shuffles traded cheap
// DS slots for expensive VALU slots + divergent lane patches. R21's
// distributed poll regressed (MALL congestion). This design family's
// optimum: temporal blocking (80 blocks, K=8, 16-row halos), creep
// gating, hoisted coefs, 1-barrier double-buffered STEP, fused export in
// sub-step 7, central 2-thread poll. Sub-steps ~730us (~90% of LDS+VALU
// pipe floor at 4 waves/SIMD), exchange ~510us (flag round-trip bound;
// K-sweep shows K=8 minimizes redundancy x epoch-count).

#define SROW 168                 // Ps row stride; col = x + 4
#define PS_ROWS 52               // slots -2..49
#define PSZ (PS_ROWS * SROW)
#define RH 2
#define DTf 0.0008f
#define C2f 1.3333333333333333f
#define C3f (-0.08333333333333333f)

#define CST_OFF 4096
#define G_OFF   262144           // bytes; 4 bufs x 10 shots x 10400 u64
#define FLAG_OFF 3590144         // bytes; 80 u32
#define GSEG 10400               // u64 per (buf, shot) = 130 rows x 80

#define LD4(arr, i) (*reinterpret_cast<const float4*>(&(arr)[i]))
#define LD2(arr, i) (*reinterpret_cast<const float2*>(&(arr)[i]))
#define ST4(arr, i, v) (*reinterpret_cast<float4*>(&(arr)[i]) = (v))

// ---------- setup 1: velmin, wavelet, amps, zero flags ----------
__global__ __launch_bounds__(1024) void fwi_setup1(const float* __restrict__ v,
                                                   float* __restrict__ ws,
                                                   unsigned int* __restrict__ flags) {
    int tid = threadIdx.x;
    if (tid < 80) flags[tid] = 0u;
    float m = 3.402823466e38f;
    for (int i = tid; i < 7000; i += 1024) m = fminf(m, v[i]);
    #pragma unroll
    for (int off = 32; off > 0; off >>= 1) m = fminf(m, __shfl_down(m, off, 64));
    __shared__ float red[16];
    if ((tid & 63) == 0) red[tid >> 6] = m;
    __syncthreads();
    if (tid == 0) {
        float mm = red[0];
        for (int i = 1; i < 16; ++i) mm = fminf(mm, red[i]);
        ws[1010] = mm * 1000.0f + 3000.0f;
    }
    if (tid < 1000) {
        float w = 0.0f;
        if (tid < 111) {
            float a = (float)(55 - tid) * 0.06283185307179587f;
            float b = a * a;
            w = (1.0f - 2.0f * b) * expf(-b);
        }
        ws[tid] = w;
    }
    if (tid >= 1000 && tid < 1010) {
        int l = tid - 1000;
        float vd = v[100 + 11 * l] * 1000.0f + 3000.0f;
        float bdt = vd * DTf;
        ws[tid] = bdt * bdt;
    }
}

// ---------- setup 2: interleaved per-quad constants CST[quad] = {AL4,T14,T2n4} ----------
__global__ __launch_bounds__(256) void fwi_setup2(const float* __restrict__ v,
                                                  const float* __restrict__ ws,
                                                  float* __restrict__ CST) {
    int c = blockIdx.x * 256 + threadIdx.x;
    if (c >= 130 * 160) return;
    float velmin = ws[1010];
    int z = c / 160;
    int x = c - z * 160;
    int iz = min(max(z - 30, 0), 69);
    int ix = min(max(x - 30, 0), 99);
    float vd = v[iz * 100 + ix] * 1000.0f + 3000.0f;
    float tt = vd * DTf / 10.0f;
    float al = tt * tt;
    int qx = max(29 - x, x - 130);
    int qz = max(29 - z, z - 100);
    int q = (qx >= 0) ? qx : qz;
    float kdt = 0.0f;
    if (q >= 0) {
        float kap3 = 3.0f * velmin * 16.118095650958319f / 580.0f;
        float r = (float)q * (10.0f / 290.0f);
        kdt = kap3 * (r * r) * DTf;
    }
    int quad = c >> 2, j = c & 3;
    CST[quad * 12 + j]     = al;
    CST[quad * 12 + 4 + j] = 2.0f - 5.0f * al - kdt;  // temp1
    CST[quad * 12 + 8 + j] = kdt - 1.0f;              // negated temp2
}

static __device__ __forceinline__ float cellq(float l2, float l1, float cc, float r1, float r2,
                                              float u1, float u2, float d1, float d2,
                                              float al, float t1, float t2n, float p0) {
    float lap = C2f * ((l1 + r1) + (u1 + d1)) + C3f * ((l2 + r2) + (u2 + d2));
    return (t1 * cc + t2n * p0) + al * lap;
}

static __device__ __forceinline__ float4 ld_remote16(const unsigned long long* p) {
    union { unsigned long long u; float2 f; } a, b;
    a.u = __hip_atomic_load(p,     __ATOMIC_RELAXED, __HIP_MEMORY_SCOPE_AGENT);
    b.u = __hip_atomic_load(p + 1, __ATOMIC_RELAXED, __HIP_MEMORY_SCOPE_AGENT);
    return make_float4(a.f.x, a.f.y, b.f.x, b.f.y);
}
static __device__ __forceinline__ void st_remote16(unsigned long long* p, float4 v) {
    union { unsigned long long u; float2 f; } c;
    c.f = make_float2(v.x, v.y);
    __hip_atomic_store(p,     c.u, __ATOMIC_RELAXED, __HIP_MEMORY_SCOPE_AGENT);
    c.f = make_float2(v.z, v.w);
    __hip_atomic_store(p + 1, c.u, __ATOMIC_RELAXED, __HIP_MEMORY_SCOPE_AGENT);
}

// One cell-row update (4 cells). Produces q from CUR/OLD regs + halos.
#define ROWQ4(q, c, p0, hl, hr, u1, u2, d1, d2, al4, t14, t24) do {             \
    (q).x = cellq((hl).x, (hl).y, (c).x, (c).y, (c).z,                          \
                  (u1).x, (u2).x, (d1).x, (d2).x, (al4).x, (t14).x, (t24).x, (p0).x); \
    (q).y = cellq((hl).y, (c).x, (c).y, (c).z, (c).w,                           \
                  (u1).y, (u2).y, (d1).y, (d2).y, (al4).y, (t14).y, (t24).y, (p0).y); \
    (q).z = cellq((c).x, (c).y, (c).z, (c).w, (hr).x,                           \
                  (u1).z, (u2).z, (d1).z, (d2).z, (al4).z, (t14).z, (t24).z, (p0).z); \
    (q).w = cellq((c).y, (c).z, (c).w, (hr).x, (hr).y,                          \
                  (u1).w, (u2).w, (d1).w, (d2).w, (al4).w, (t14).w, (t24).w, (p0).w); \
} while (0)

// One sub-step (RH=2). CUR = p1 regs (read-only), OLD = p0 regs (overwritten
// with new p1). K = sub-step index (0..7) for validity creep. EXPF: inline
// epoch export (k==7 only; creep-active set == interior owners there).
#define STEP(CUR, OLD, T, K, EXPF, EPAR, PR, PW) do {                           \
    const int Ti = (T);                                                         \
    const int kp1 = (K) + 1;                                                    \
    const bool actk = act && (gr >= (ct ? kp1 : 0)) && (gr < ng - (cb ? kp1 : 0)); \
    const float as = (Ti < 111) ? amp * Wv[Ti] : 0.0f;                          \
    if (actk) {                                                                 \
        float4 hu2 = LD4(PR, pc0 - 2 * SROW);                                   \
        float4 hu1 = LD4(PR, pc0 - SROW);                                       \
        float4 hd1 = LD4(PR, pc0 + 2 * SROW);                                   \
        float4 hd2 = LD4(PR, pc0 + 3 * SROW);                                   \
        float2 hl0 = LD2(PR, pc0 - 2);                                          \
        float2 hr0 = LD2(PR, pc0 + 4);                                          \
        float2 hl1 = LD2(PR, pc0 + SROW - 2);                                   \
        float2 hr1 = LD2(PR, pc0 + SROW + 4);                                   \
        float4 q0, q1;                                                          \
        ROWQ4(q0, (CUR)[0], (OLD)[0], hl0, hr0, hu1, hu2, (CUR)[1], hd1, ca0, ct0, cs0); \
        ROWQ4(q1, (CUR)[1], (OLD)[1], hl1, hr1, (CUR)[0], hu1, hd1, hd2, ca1, ct1, cs1); \
        if (src0) {                                /* source row at slot gr*2 */ \
            q0.x += (ls == 0) ? as : 0.0f;                                      \
            q0.y += (ls == 1) ? as : 0.0f;                                      \
            q0.z += (ls == 2) ? as : 0.0f;                                      \
            q0.w += (ls == 3) ? as : 0.0f;                                      \
        }                                                                       \
        if (src1) {                                /* source row at slot gr*2+1 */ \
            q1.x += (ls == 0) ? as : 0.0f;                                      \
            q1.y += (ls == 1) ? as : 0.0f;                                      \
            q1.z += (ls == 2) ? as : 0.0f;                                      \
            q1.w += (ls == 3) ? as : 0.0f;                                      \
        }                                                                       \
        if (grec) {                                /* receivers: global row 31 */ \
            const int ob = shot * 100000 + Ti * 100 + xr0;                      \
            if (xr0 >= 0  && xr0 <= 99) out[ob]     = q1.x;                     \
            if (xr0 >= -1 && xr0 <= 98) out[ob + 1] = q1.y;                     \
            if (xr0 >= -2 && xr0 <= 97) out[ob + 2] = q1.z;                     \
            if (xr0 >= -3 && xr0 <= 96) out[ob + 3] = q1.w;                     \
        }                                                                       \
        if ((EXPF) && exp01) {                     /* inline epoch export */    \
            const size_t po = (size_t)((EPAR) * 20) * GSEG;                     \
            st_remote16(Gu + po + eb0, q0);                                     \
            st_remote16(Gu + po + (size_t)10 * GSEG + eb0, (CUR)[0]);           \
            st_remote16(Gu + po + eb1, q1);                                     \
            st_remote16(Gu + po + (size_t)10 * GSEG + eb1, (CUR)[1]);           \
        }                                                                       \
        (OLD)[0] = q0; (OLD)[1] = q1;                                           \
        ST4(PW, pc0, q0);                                                       \
        ST4(PW, pc0 + SROW, q1);                                                \
    }                                                                           \
    __syncthreads();            /* PW complete, PR reads done, exports drained */ \
} while (0)

// Epoch exchange tail: flag release + CENTRAL poll (2 threads) + barrier +
// relaxed import + barrier. R16/R20-proven happens-before chain.
#define EXCHANGE(E) do {                                                        \
    const int par = (E) & 1;                                                    \
    const size_t po1 = (size_t)(par * 20) * GSEG;                               \
    const size_t po0 = po1 + (size_t)10 * GSEG;                                 \
    if (tid == 0)                                                               \
        __hip_atomic_store(&flags[(shot << 3) + seg], (unsigned)(E) + 1u,       \
                           __ATOMIC_RELEASE, __HIP_MEMORY_SCOPE_AGENT);         \
    if (tid == 64 && ct)                                                        \
        while (__hip_atomic_load(&flags[(shot << 3) + seg - 1], __ATOMIC_ACQUIRE,\
                                 __HIP_MEMORY_SCOPE_AGENT) <= (unsigned)(E)) {} \
    if (tid == 128 && cb)                                                       \
        while (__hip_atomic_load(&flags[(shot << 3) + seg + 1], __ATOMIC_ACQUIRE,\
                                 __HIP_MEMORY_SCOPE_AGENT) <= (unsigned)(E)) {} \
    __syncthreads();                        /* neighbors' data ready */         \
    if (act && halo_thr) {                                                      \
        float4 v1a = ld_remote16(Gu + po1 + eb0);                               \
        float4 v0a = ld_remote16(Gu + po0 + eb0);                               \
        float4 v1b = ld_remote16(Gu + po1 + eb1);                               \
        float4 v0b = ld_remote16(Gu + po0 + eb1);                               \
        pB[0] = v1a; pA[0] = v0a;                                               \
        pB[1] = v1b; pA[1] = v0b;                                               \
        ST4(PsA, pc0, v1a);                                                     \
        ST4(PsA, pc0 + SROW, v1b);                                              \
    }                                                                           \
    __syncthreads();                        /* imported PsA/regs visible */     \
} while (0)

// ---------- main: 80 blocks = 10 shots x 8 z-segments, 1024 threads ----------
__global__ __launch_bounds__(1024, 4) void fwi_main(const float4* __restrict__ CST4,
                                                    const float* __restrict__ ws,
                                                    unsigned long long* __restrict__ Gu,
                                                    unsigned int* __restrict__ flags,
                                                    float* __restrict__ out) {
    __shared__ float PsA[PSZ];     // p1 mirror, even-T read buffer (34,944 B)
    __shared__ float PsB[PSZ];     // p1 mirror, odd-T read buffer (34,944 B)
    __shared__ float Wv[1024];     // wavelet, zero-padded
    const int tid = threadIdx.x;
    const int bid = blockIdx.x;
    const int shot = bid >> 3, seg = bid & 7;

    for (int i = tid; i < PSZ; i += 1024) { PsA[i] = 0.0f; PsB[i] = 0.0f; }
    Wv[tid] = (tid < 111) ? ws[tid] : 0.0f;

    const int int_base = 16 * seg;                 // interior global start row
    const int int_n = (seg < 7) ? 16 : 18;         // interior rows
    const int base = (seg > 0) ? int_base - 16 : 0;// stored global start row
    const int halo_top = (seg > 0) ? 16 : 0;
    const int stored_n = halo_top + int_n + ((seg < 7) ? 16 : 0); // 32|48|34 (even)
    const bool ct = (seg > 0);                     // top cut exists
    const bool cb = (seg < 7);                     // bottom cut exists
    const int ng = stored_n >> 1;                  // groups covering stored rows

    const int gr = tid / 40;                       // z-group 0..24 (RH=2 rows)
    const int qx = tid - gr * 40;                  // x-quad 0..39
    const bool act = (gr < 24) && (gr * 2 < stored_n);
    const float amp = ws[1000 + shot];
    const int xs = 30 + 11 * shot;
    const bool isq = (qx == (xs >> 2));
    const int ls = xs & 3;
    const int s31 = 31 - base;                     // stored slot of source row
    const bool src0 = act && isq && (gr * 2 == s31);
    const bool src1 = act && isq && (gr * 2 + 1 == s31);
    const int pc0 = (gr * 2 + 2) * SROW + 4 * qx + 4;
    const float4* cst = CST4 + (size_t)((base + gr * 2) * 40 + qx) * 3;
    const bool grec = (seg == 1) && (gr == 15);    // slot 31 = global row 31 (r=1)
    const int xr0 = 4 * qx - 30;                   // receiver index of lane j=0

    // exchange addressing (group-aligned: interior/halo bounds are even)
    const int slot0 = gr * 2;
    const bool exp01 = (slot0 >= halo_top) && (slot0 < halo_top + int_n);
    const bool top_h = (slot0 < halo_top);                    // implies seg>0
    const bool bot_h = (slot0 >= halo_top + int_n) && (slot0 < stored_n); // implies seg<7
    const bool halo_thr = top_h || bot_h;
    const size_t eb0 = (size_t)shot * GSEG + (size_t)(base + slot0) * 80 + 2 * qx;
    const size_t eb1 = eb0 + 80;

    // hoisted time-invariant coefficients (24 VGPRs)
    float4 ca0, ct0, cs0, ca1, ct1, cs1;
    ca0 = ct0 = cs0 = ca1 = ct1 = cs1 = make_float4(0.f, 0.f, 0.f, 0.f);
    if (act) {
        ca0 = cst[0];   ct0 = cst[1];   cs0 = cst[2];
        ca1 = cst[120]; ct1 = cst[121]; cs1 = cst[122];
    }

    float4 pA[RH], pB[RH];                         // two generations in regs
    #pragma unroll
    for (int r = 0; r < RH; ++r) {
        pA[r] = make_float4(0.f, 0.f, 0.f, 0.f);
        pB[r] = make_float4(0.f, 0.f, 0.f, 0.f);
    }
    __syncthreads();

    for (int e = 0; e < 125; ++e) {                // 125 epochs x 8 sub-steps
        #pragma unroll
        for (int kk = 0; kk < 4; ++kk) {
            STEP(pB, pA, e * 8 + 2 * kk,     2 * kk,     false,      0,     PsA, PsB);
            STEP(pA, pB, e * 8 + 2 * kk + 1, 2 * kk + 1, (kk == 3), (e & 1), PsB, PsA);
        }
        if (e < 124) EXCHANGE(e);
    }
}

extern "C" void kernel_launch(void* const* d_in, const int* in_sizes, int n_in,
                              void* d_out, int out_size, void* d_ws, size_t ws_size,
                              hipStream_t stream) {
    const float* v = (const float*)d_in[0];
    float* ws = (float*)d_ws;
    float* CST = (float*)((char*)d_ws + CST_OFF);
    unsigned long long* Gu = (unsigned long long*)((char*)d_ws + G_OFF);
    unsigned int* flags = (unsigned int*)((char*)d_ws + FLAG_OFF);
    float* out = (float*)d_out;

    fwi_setup1<<<1, 1024, 0, stream>>>(v, ws, flags);
    fwi_setup2<<<82, 256, 0, stream>>>(v, ws, CST);
    fwi_main<<<80, 1024, 0, stream>>>((const float4*)CST, ws, Gu, flags, out);
}